// Round 4
// baseline (376.692 us; speedup 1.0000x reference)
//
#include <hip/hip_runtime.h>
#include <math.h>

// Problem constants (from reference setup_inputs)
constexpr int B = 4;
constexpr int N = 512;     // rois per batch
constexpr int C = 256;     // channels
constexpr int H = 256;
constexpr int W = 256;
constexpr int NPT = 5;     // center, front, back, left, right
constexpr int PTS = N * NPT;   // 2560 points per batch

constexpr int RT  = 8;         // rows per y-tile
constexpr int NT  = H / RT;    // 32 tiles
constexpr int CG  = 4;         // channels per block (== waves per block)
constexpr int NCG = C / CG;    // 64 channel groups
// per-channel LDS slab: 9 dense rows x 256 floats; +8 float pad between slabs
// so channel bases sit 8 banks apart (2312 % 32 == 8) for the 4-way fan-out.
constexpr int SLAB = (RT + 1) * W + 8;   // 2312 floats
constexpr int CAPL = 768;      // LDS point-list capacity (avg ~90/tile, 8x margin)

// xs = (x + 51.2) * 2.5

__device__ __forceinline__ void async16(const float* g, float* l) {
#if defined(__has_builtin) && __has_builtin(__builtin_amdgcn_global_load_lds)
    __builtin_amdgcn_global_load_lds(
        (const __attribute__((address_space(1))) unsigned int*)g,
        (__attribute__((address_space(3))) unsigned int*)l, 16, 0, 0);
#else
    // fallback: plain vector copy through VGPRs
    *(float4*)l = *(const float4*)g;
#endif
}

__global__ __launch_bounds__(256)
void bev_fused(const float* __restrict__ feats,  // (B,C,H,W)
               const float* __restrict__ rois,   // (B,N,7)
               float* __restrict__ out)          // (B,N,NPT*C)
{
    const int t   = blockIdx.x;   // y-tile [0,32)
    const int cg  = blockIdx.y;   // channel group [0,64)
    const int b   = blockIdx.z;   // batch [0,4)
    const int tid = threadIdx.x;
    const int wave = tid >> 6;    // [0,4) == channel within group
    const int lane = tid & 63;

    __shared__ __align__(16) float slab[CG * SLAB];
    __shared__ float    lxs[CAPL];
    __shared__ float    lys[CAPL];
    __shared__ unsigned lnp[CAPL];
    __shared__ unsigned lcnt;

    if (tid == 0) lcnt = 0u;
    __syncthreads();

    // ---- Phase 1: geometry scan of this batch's 2560 points (rois L2-hot) ----
    for (int q = tid; q < PTS; q += 256) {
        const int n = q / NPT;
        const int p = q - n * NPT;
        const float* roi = rois + ((size_t)b * N + n) * 7;
        const float cx = roi[0], cy = roi[1];
        const float hx = 0.5f * roi[3];
        const float hy = 0.5f * roi[4];
        float si, co;
        sincosf(roi[6], &si, &co);
        float px = cx, py = cy;
        if      (p == 1) { px -= hx * co; py += hx * si; }  // front
        else if (p == 2) { px += hx * co; py -= hx * si; }  // back
        else if (p == 3) { px -= hy * si; py -= hy * co; }  // left
        else if (p == 4) { px += hy * si; py += hy * co; }  // right
        const float xs = (px + 51.2f) * 2.5f;
        const float ys = (py + 51.2f) * 2.5f;

        const int yi = (int)floorf(ys);
        const int y0 = min(max(yi, 0), H - 1);
        if ((y0 >> 3) != t) continue;

        const unsigned slot = atomicAdd(&lcnt, 1u);
        if (slot < CAPL) {
            lxs[slot] = xs; lys[slot] = ys;
            lnp[slot] = (unsigned)((n << 3) | p);
        } else {
            // overflow safety net (never hit for this data): direct global path
            const int xi = (int)floorf(xs);
            const int x0 = min(max(xi, 0), W - 1);
            const int x1 = min(max(xi + 1, 0), W - 1);
            const int y1 = min(max(yi + 1, 0), H - 1);
            const float x0f = (float)x0, x1f = (float)x1;
            const float y0f = (float)y0, y1f = (float)y1;
            const float wa = (x1f - xs) * (y1f - ys);
            const float wb = (x1f - xs) * (ys - y0f);
            const float wc = (xs - x0f) * (y1f - ys);
            const float wd = (xs - x0f) * (ys - y0f);
            for (int ch = 0; ch < CG; ++ch) {
                const float* fp = feats + ((size_t)b * C + cg * CG + ch) * (H * W);
                const float v = fp[y0 * W + x0] * wa + fp[y1 * W + x0] * wb +
                                fp[y0 * W + x1] * wc + fp[y1 * W + x1] * wd;
                out[(((size_t)b * N + n) * NPT + p) * C + cg * CG + ch] = v;
            }
        }
    }
    __syncthreads();
    const unsigned m = min(lcnt, (unsigned)CAPL);
    if (m == 0) return;   // uniform: empty tile, skip staging entirely

    // ---- Phase 2: async stage CG planes x 9 rows (8 on last tile) ----
    // wave w streams channel w: row j is one dense 1 KB row; LDS dest is
    // wave-uniform base + lane*16 (global_load_lds addressing contract).
    const int nrows = (t == NT - 1) ? RT : (RT + 1);
    {
        const float* g = feats + (((size_t)b * C + cg * CG + wave) * H + t * RT) * W
                         + lane * 4;
        float* l = slab + wave * SLAB;
        for (int j = 0; j < nrows; ++j)
            async16(g + j * W, l + j * W);
    }
    __syncthreads();

    // ---- Phase 3: 4 threads per point (one per channel); 16B/pt stores ----
    const int ch = tid & 3;
    const int pi = tid >> 2;
    const float* sl = slab + ch * SLAB;

    for (unsigned i = pi; i < m; i += 64) {
        const float xs = lxs[i];
        const float ys = lys[i];
        const unsigned np = lnp[i];

        const int xi = (int)floorf(xs);
        const int yi = (int)floorf(ys);
        const int x0 = min(max(xi, 0), W - 1);
        const int x1 = min(max(xi + 1, 0), W - 1);
        const int y0 = min(max(yi, 0), H - 1);
        const int y1 = min(max(yi + 1, 0), H - 1);

        const float x0f = (float)x0, x1f = (float)x1;
        const float y0f = (float)y0, y1f = (float)y1;
        const float wa = (x1f - xs) * (y1f - ys);
        const float wb = (x1f - xs) * (ys - y0f);
        const float wc = (xs - x0f) * (y1f - ys);
        const float wd = (xs - x0f) * (ys - y0f);

        const int ly0 = y0 - t * RT;   // [0,7]
        const int ly1 = y1 - t * RT;   // [0,8]

        const float v = sl[ly0 * W + x0] * wa + sl[ly1 * W + x0] * wb +
                        sl[ly0 * W + x1] * wc + sl[ly1 * W + x1] * wd;

        out[(((size_t)b * N + (np >> 3)) * NPT + (np & 7)) * C + cg * CG + ch] = v;
    }
}

extern "C" void kernel_launch(void* const* d_in, const int* in_sizes, int n_in,
                              void* d_out, int out_size, void* d_ws, size_t ws_size,
                              hipStream_t stream) {
    const float* feats = (const float*)d_in[0];  // (B,C,H,W) f32
    const float* rois  = (const float*)d_in[1];  // (B,N,7)   f32
    float* out = (float*)d_out;                  // (B,N,NPT*C) f32

    bev_fused<<<dim3(NT, NCG, B), dim3(256), 0, stream>>>(feats, rois, out);
}